// Round 1
// baseline (8022.443 us; speedup 1.0000x reference)
//
#include <hip/hip_runtime.h>
#include <hip/hip_bf16.h>
#include <math.h>

#define B_   64
#define L_   2048
#define D_   512
#define EPS  2e-5f

typedef _Float16 h2t __attribute__((ext_vector_type(2)));

union PackU { unsigned u; h2t v; _Float16 h[2]; };

__device__ inline float fdot2f(unsigned wu, unsigned hu, float acc) {
#if __has_builtin(__builtin_amdgcn_fdot2)
    PackU a, b; a.u = wu; b.u = hu;
    return __builtin_amdgcn_fdot2(a.v, b.v, acc, false);
#else
    PackU a, b; a.u = wu; b.u = hu;
    return acc + (float)a.h[0] * (float)b.h[0] + (float)a.h[1] * (float)b.h[1];
#endif
}

// blocks [0,64): compute u[b][d] = x[b]·W_ih[d] + b_ih[d] + b_hh[d]
// blocks [64,128): transpose+convert W_hh -> WT8 packed f16 pairs:
//   WT8 row k8 (k8 in [0,64)) holds, per d, uint4 = 4 packed pairs covering k = 8*k8 .. 8*k8+7
__global__ __launch_bounds__(512) void prep_kernel(
    const float* __restrict__ x, const float* __restrict__ W_ih,
    const float* __restrict__ W_hh, const float* __restrict__ b_ih,
    const float* __restrict__ b_hh, uint4* __restrict__ wt8,
    float* __restrict__ u)
{
    const int blk = blockIdx.x;
    const int tid = threadIdx.x;
    if (blk < B_) {
        __shared__ float xs[D_];
        xs[tid] = x[blk * D_ + tid];
        __syncthreads();
        const float4* wrow = reinterpret_cast<const float4*>(W_ih + (size_t)tid * D_);
        const float4* xv   = reinterpret_cast<const float4*>(xs);
        float acc = b_ih[tid] + b_hh[tid];
        #pragma unroll 8
        for (int k = 0; k < D_ / 4; ++k) {
            float4 w = wrow[k]; float4 xx = xv[k];
            acc += w.x * xx.x + w.y * xx.y + w.z * xx.z + w.w * xx.w;
        }
        u[blk * D_ + tid] = acc;
    } else {
        const int k8 = blk - B_;                   // [0,64)
        const float* wr = W_hh + (size_t)tid * D_ + k8 * 8;
        unsigned o[4];
        #pragma unroll
        for (int j = 0; j < 4; ++j) {
            PackU p;
            p.h[0] = (_Float16)wr[2 * j];
            p.h[1] = (_Float16)wr[2 * j + 1];
            o[j] = p.u;
        }
        wt8[(size_t)k8 * D_ + tid] = make_uint4(o[0], o[1], o[2], o[3]);
    }
}

// One block per sample. Thread d owns output element d.
// h (prev step) lives packed-f16 in LDS; dot via v_dot2_f32_f16.
// Early exit when max|h_t - h_{t-1}| <= EPS (autonomous contraction -> fixed point).
__global__ __launch_bounds__(512) void rnn_kernel(
    const int* __restrict__ counts, const float* __restrict__ u,
    const uint4* __restrict__ wt8, float* __restrict__ out,
    float* __restrict__ hstar, int* __restrict__ tstop)
{
    const int b = blockIdx.x;
    const int d = threadIdx.x;
    int count = counts[b];
    if (count > L_) count = L_;
    if (count < 0) count = 0;

    __shared__ __align__(16) _Float16 h16[D_];
    __shared__ int flag;
    h16[d] = (_Float16)0.f;
    if (d == 0) flag = -1;
    __syncthreads();

    const float ureg = u[b * D_ + d];
    const uint4* hv  = reinterpret_cast<const uint4*>(h16);
    float* orow = out + (size_t)b * L_ * D_ + d;

    float hprev = 0.f;
    float h     = 0.f;
    int   t     = 0;
    for (t = 0; t < count; ++t) {
        float acc = ureg;
        #pragma unroll 8
        for (int k8 = 0; k8 < D_ / 8; ++k8) {
            uint4 w  = wt8[(size_t)k8 * D_ + d];   // coalesced, L2-resident
            uint4 hh = hv[k8];                     // uniform LDS broadcast
            acc = fdot2f(w.x, hh.x, acc);
            acc = fdot2f(w.y, hh.y, acc);
            acc = fdot2f(w.z, hh.z, acc);
            acc = fdot2f(w.w, hh.w, acc);
        }
        h = tanhf(acc);
        orow[(size_t)t * D_] = h;

        const float diff = fabsf(h - hprev);
        hprev = h;
        __syncthreads();                 // everyone done reading h16 of prev step
        h16[d] = (_Float16)h;
        if (diff > EPS) flag = t;        // benign same-value race
        __syncthreads();                 // h16 + flag visible
        if (flag != t) { ++t; break; }   // converged: rows [t, count) all == h
    }

    hstar[b * D_ + d] = h;
    if (d == 0) tstop[b] = t;
}

// Write rows [tstop, count) = hstar, rows [count, L) = 0. Rows [0,tstop) already written.
__global__ __launch_bounds__(256) void fill_kernel(
    const int* __restrict__ counts, const int* __restrict__ tstop,
    const float* __restrict__ hstar, float* __restrict__ out)
{
    const int b   = blockIdx.y;
    const int c   = blockIdx.x;          // 128 chunks of 16 rows
    const int tid = threadIdx.x;
    int count = counts[b];
    if (count > L_) count = L_;
    if (count < 0) count = 0;
    const int ts  = tstop[b];

    const int d4   = tid & 127;
    const int rsub = tid >> 7;           // 0..1
    const float4 hv = reinterpret_cast<const float4*>(hstar + (size_t)b * D_)[d4];
    const float4 z  = make_float4(0.f, 0.f, 0.f, 0.f);
    float4* ob = reinterpret_cast<float4*>(out + (size_t)b * L_ * D_);

    #pragma unroll
    for (int rr = 0; rr < 8; ++rr) {
        const int t = c * 16 + rr * 2 + rsub;
        if (t < ts) continue;
        ob[(size_t)t * (D_ / 4) + d4] = (t < count) ? hv : z;
    }
}

extern "C" void kernel_launch(void* const* d_in, const int* in_sizes, int n_in,
                              void* d_out, int out_size, void* d_ws, size_t ws_size,
                              hipStream_t stream) {
    const int*   counts = (const int*)d_in[0];
    const float* x      = (const float*)d_in[1];
    const float* W_ih   = (const float*)d_in[2];
    const float* W_hh   = (const float*)d_in[3];
    const float* b_ih   = (const float*)d_in[4];
    const float* b_hh   = (const float*)d_in[5];
    float* out = (float*)d_out;

    char* ws = (char*)d_ws;
    uint4* wt8   = (uint4*)ws;                                  // 512 KB
    float* u     = (float*)(ws + (512 << 10));                  // 128 KB
    float* hstar = (float*)(ws + (512 << 10) + (128 << 10));    // 128 KB
    int*   tstop = (int*)  (ws + (512 << 10) + (256 << 10));    // 256 B

    hipLaunchKernelGGL(prep_kernel, dim3(128), dim3(512), 0, stream,
                       x, W_ih, W_hh, b_ih, b_hh, wt8, u);
    hipLaunchKernelGGL(rnn_kernel, dim3(B_), dim3(512), 0, stream,
                       counts, u, wt8, out, hstar, tstop);
    hipLaunchKernelGGL(fill_kernel, dim3(128, B_), dim3(256), 0, stream,
                       counts, tstop, hstar, out);
}

// Round 2
// 125.058 us; speedup vs baseline: 64.1499x; 64.1499x over previous
//
#include <hip/hip_runtime.h>
#include <hip/hip_bf16.h>
#include <math.h>

#define B_   64
#define L_   2048
#define D_   512
#define EPS  6e-4f   // period-2 convergence threshold on f32 h (above f16 noise floor)

typedef _Float16 h2t __attribute__((ext_vector_type(2)));

union PackU { unsigned u; h2t v; _Float16 h[2]; };

__device__ inline float fdot2f(unsigned wu, unsigned hu, float acc) {
#if __has_builtin(__builtin_amdgcn_fdot2)
    PackU a, b; a.u = wu; b.u = hu;
    return __builtin_amdgcn_fdot2(a.v, b.v, acc, false);
#else
    PackU a, b; a.u = wu; b.u = hu;
    return acc + (float)a.h[0] * (float)b.h[0] + (float)a.h[1] * (float)b.h[1];
#endif
}

// blocks [0,64): u[b][d] = x[b]·W_ih[d] + b_ih[d] + b_hh[d]
// blocks [64,128): transpose+convert W_hh -> WT8 packed f16 pairs:
//   WT8 row k8 in [0,64) holds, per d, uint4 = 4 packed pairs covering k = 8*k8..8*k8+7
__global__ __launch_bounds__(512) void prep_kernel(
    const float* __restrict__ x, const float* __restrict__ W_ih,
    const float* __restrict__ W_hh, const float* __restrict__ b_ih,
    const float* __restrict__ b_hh, uint4* __restrict__ wt8,
    float* __restrict__ u)
{
    const int blk = blockIdx.x;
    const int tid = threadIdx.x;
    if (blk < B_) {
        __shared__ float xs[D_];
        xs[tid] = x[blk * D_ + tid];
        __syncthreads();
        const float4* wrow = reinterpret_cast<const float4*>(W_ih + (size_t)tid * D_);
        const float4* xv   = reinterpret_cast<const float4*>(xs);
        float acc = b_ih[tid] + b_hh[tid];
        #pragma unroll 8
        for (int k = 0; k < D_ / 4; ++k) {
            float4 w = wrow[k]; float4 xx = xv[k];
            acc += w.x * xx.x + w.y * xx.y + w.z * xx.z + w.w * xx.w;
        }
        u[blk * D_ + tid] = acc;
    } else {
        const int k8 = blk - B_;
        const float* wr = W_hh + (size_t)tid * D_ + k8 * 8;
        unsigned o[4];
        #pragma unroll
        for (int j = 0; j < 4; ++j) {
            PackU p;
            p.h[0] = (_Float16)wr[2 * j];
            p.h[1] = (_Float16)wr[2 * j + 1];
            o[j] = p.u;
        }
        wt8[(size_t)k8 * D_ + tid] = make_uint4(o[0], o[1], o[2], o[3]);
    }
}

// One block per sample; thread d owns output element d. W row lives in
// 256 VGPRs (loaded once); h lives packed-f16 in LDS (uniform broadcast
// reads). Early exit on period-2 fixed point: |h_t - h_{t-2}| <= EPS.
__global__ __launch_bounds__(512, 2) void rnn_kernel(
    const int* __restrict__ counts, const float* __restrict__ u,
    const uint4* __restrict__ wt8, float* __restrict__ out,
    float* __restrict__ hA, float* __restrict__ hB, int* __restrict__ tstop)
{
    const int b = blockIdx.x;
    const int d = threadIdx.x;
    int count = counts[b];
    if (count > L_) count = L_;
    if (count < 0) count = 0;

    __shared__ __align__(16) _Float16 h16[D_];
    __shared__ int flag;
    h16[d] = (_Float16)0.f;
    if (d == 0) flag = -1;

    // W row d -> registers (64 x uint4 = 256 VGPRs), fully static indexing.
    uint4 wreg[64];
    #pragma unroll
    for (int k8 = 0; k8 < 64; ++k8) wreg[k8] = wt8[(size_t)k8 * D_ + d];

    const float ureg = u[b * D_ + d];
    const uint4* hv  = reinterpret_cast<const uint4*>(h16);
    float* orow = out + (size_t)b * L_ * D_ + d;
    __syncthreads();

    float hcur = 0.f, hprev = 0.f, hprev2 = 0.f;
    int   ts   = count;           // default: ran to completion
    float a_out = 0.f, b_out = 0.f;

    for (int t = 0; t < count; ++t) {
        float acc0 = ureg, acc1 = 0.f, acc2 = 0.f, acc3 = 0.f;
        #pragma unroll
        for (int k8 = 0; k8 < 64; k8 += 4) {
            uint4 w0 = wreg[k8 + 0], w1 = wreg[k8 + 1];
            uint4 w2 = wreg[k8 + 2], w3 = wreg[k8 + 3];
            uint4 h0 = hv[k8 + 0],  h1 = hv[k8 + 1];
            uint4 h2 = hv[k8 + 2],  h3 = hv[k8 + 3];
            acc0 = fdot2f(w0.x, h0.x, acc0); acc0 = fdot2f(w0.y, h0.y, acc0);
            acc0 = fdot2f(w0.z, h0.z, acc0); acc0 = fdot2f(w0.w, h0.w, acc0);
            acc1 = fdot2f(w1.x, h1.x, acc1); acc1 = fdot2f(w1.y, h1.y, acc1);
            acc1 = fdot2f(w1.z, h1.z, acc1); acc1 = fdot2f(w1.w, h1.w, acc1);
            acc2 = fdot2f(w2.x, h2.x, acc2); acc2 = fdot2f(w2.y, h2.y, acc2);
            acc2 = fdot2f(w2.z, h2.z, acc2); acc2 = fdot2f(w2.w, h2.w, acc2);
            acc3 = fdot2f(w3.x, h3.x, acc3); acc3 = fdot2f(w3.y, h3.y, acc3);
            acc3 = fdot2f(w3.z, h3.z, acc3); acc3 = fdot2f(w3.w, h3.w, acc3);
        }
        const float h = tanhf((acc0 + acc1) + (acc2 + acc3));
        orow[(size_t)t * D_] = h;

        hprev2 = hprev; hprev = hcur; hcur = h;
        const float diff2 = fabsf(hcur - hprev2);

        __syncthreads();                    // all reads of h16 done
        h16[d] = (_Float16)h;
        if (t < 2 || diff2 > EPS) flag = t; // benign same-value race
        __syncthreads();                    // h16 + flag visible
        if (flag != t) {                    // period-2 fixed point reached
            ts = t + 1;                     // rows [ts,count): alternate hprev,hcur
            a_out = hprev;                  // row ts       (parity 0)
            b_out = hcur;                   // row ts + 1   (parity 1)
            break;
        }
    }

    hA[b * D_ + d] = a_out;
    hB[b * D_ + d] = b_out;
    if (d == 0) tstop[b] = ts;
}

// Rows [ts,count): alternate hA/hB by parity of (t-ts). Rows [count,L): 0.
__global__ __launch_bounds__(256) void fill_kernel(
    const int* __restrict__ counts, const int* __restrict__ tstop,
    const float* __restrict__ hA, const float* __restrict__ hB,
    float* __restrict__ out)
{
    const int b   = blockIdx.y;
    const int c   = blockIdx.x;          // 128 chunks of 16 rows
    const int tid = threadIdx.x;
    int count = counts[b];
    if (count > L_) count = L_;
    if (count < 0) count = 0;
    const int ts  = tstop[b];

    const int d4   = tid & 127;
    const int rsub = tid >> 7;           // 0..1
    const float4 av = reinterpret_cast<const float4*>(hA + (size_t)b * D_)[d4];
    const float4 bv = reinterpret_cast<const float4*>(hB + (size_t)b * D_)[d4];
    const float4 z  = make_float4(0.f, 0.f, 0.f, 0.f);
    float4* ob = reinterpret_cast<float4*>(out + (size_t)b * L_ * D_);

    #pragma unroll
    for (int rr = 0; rr < 8; ++rr) {
        const int t = c * 16 + rr * 2 + rsub;
        if (t < ts) continue;
        float4 v = z;
        if (t < count) v = ((t - ts) & 1) ? bv : av;
        ob[(size_t)t * (D_ / 4) + d4] = v;
    }
}

extern "C" void kernel_launch(void* const* d_in, const int* in_sizes, int n_in,
                              void* d_out, int out_size, void* d_ws, size_t ws_size,
                              hipStream_t stream) {
    const int*   counts = (const int*)d_in[0];
    const float* x      = (const float*)d_in[1];
    const float* W_ih   = (const float*)d_in[2];
    const float* W_hh   = (const float*)d_in[3];
    const float* b_ih   = (const float*)d_in[4];
    const float* b_hh   = (const float*)d_in[5];
    float* out = (float*)d_out;

    char* ws = (char*)d_ws;
    uint4* wt8 = (uint4*)ws;                                   // 512 KB
    float* u   = (float*)(ws + (512 << 10));                   // 128 KB
    float* hA  = (float*)(ws + (512 << 10) + (128 << 10));     // 128 KB
    float* hB  = (float*)(ws + (512 << 10) + (256 << 10));     // 128 KB
    int*   tstop = (int*)(ws + (512 << 10) + (384 << 10));     // 256 B

    hipLaunchKernelGGL(prep_kernel, dim3(128), dim3(512), 0, stream,
                       x, W_ih, W_hh, b_ih, b_hh, wt8, u);
    hipLaunchKernelGGL(rnn_kernel, dim3(B_), dim3(512), 0, stream,
                       counts, u, wt8, out, hA, hB, tstop);
    hipLaunchKernelGGL(fill_kernel, dim3(128, B_), dim3(256), 0, stream,
                       counts, tstop, hA, hB, out);
}